// Round 6
// baseline (213.714 us; speedup 1.0000x reference)
//
#include <hip/hip_runtime.h>

namespace {
constexpr int HIN = 130, WIN = 130;
constexpr int HH = 128, WW = 128;
constexpr int C = 128, CR = 32, B = 8;
constexpr int CHW = HIN * WIN;   // 16900

// Transpose W_reduce (32x128) -> WredT (128x32): r-loop reads contiguous
// uniform floats (scalarized to s_load_dwordx*).
__global__ void transpose_wred(const float* __restrict__ Wred, float* __restrict__ WredT) {
    int idx = blockIdx.x * 256 + threadIdx.x;   // 4096 elements
    int r = idx >> 7;
    int c = idx & 127;
    WredT[c * CR + r] = Wred[r * C + c];
}

// In-wave LDS ordering fence (rule-18 pattern): cross-lane write->read in
// wave-private LDS is invisible to per-lane alias analysis; lgkmcnt(0) +
// sched_barrier(0) orders it without a workgroup barrier.
__device__ __forceinline__ void lds_fence() {
    asm volatile("s_waitcnt lgkmcnt(0)" ::: "memory");
    __builtin_amdgcn_sched_barrier(0);
}

// lgkm-only workgroup barrier: leaves global prefetch (vmcnt) in flight.
__device__ __forceinline__ void lgkm_barrier() {
    asm volatile("s_waitcnt lgkmcnt(0)\n\ts_barrier" ::: "memory");
    __builtin_amdgcn_sched_barrier(0);
}

// Block = 256 threads = 64 pixels (lanes) x 4 waves.
// Wave q owns channels [32q,32q+32) and groups {2q,2q+1}. red_lds and the
// stage-3 tap buffer OVERLAY each other (union) -> 12.7 KB/block -> 8
// blocks/CU resident = entire 2048-block grid, no tail.
__global__ __launch_bounds__(256, 8) void invol_fused(
    const float* __restrict__ x,      // [B][C][130][130]
    const float* __restrict__ WredT,  // [128][32]
    const float* __restrict__ bred,   // [32]
    const float* __restrict__ Wkern,  // [72][32]
    const float* __restrict__ bkern,  // [72]
    float* __restrict__ out)          // [B][C][128][128]
{
    __shared__ union SM {
        float red[64][CR + 1];   // 8448 B   (stage 1/2)
        float xs[4][12][66];     // 12672 B  (stage 3, wave-private rows)
    } sm;

    const int t = threadIdx.x;
    const int p = t & 63;
    const int q = __builtin_amdgcn_readfirstlane(t >> 6);

    // XCD-chunked swizzle: XCD k owns batch k -> h-adjacent blocks (sharing
    // 2/3 of their row footprint) land on the same L2.
    const int orig = blockIdx.x;
    const int blk  = (orig & 7) * 256 + (orig >> 3);   // bijective (2048 % 8 == 0)
    const int b    = blk >> 8;
    const int h    = (blk >> 1) & (HH - 1);
    const int w0   = (blk & 1) << 6;

    const float* xb = x + (size_t)b * C * CHW;

    // ---- stage 1: red[8q..8q+8) ----
    const float* xc = xb + (size_t)(h + 1) * WIN + (w0 + p + 1);
    float racc[8];
#pragma unroll
    for (int r = 0; r < 8; ++r) racc[r] = bred[q * 8 + r];

#pragma unroll
    for (int cb = 0; cb < 4; ++cb) {
        float xv[32];
#pragma unroll
        for (int cc = 0; cc < 32; ++cc)
            xv[cc] = xc[(size_t)(cb * 32 + cc) * CHW];
#pragma unroll
        for (int cc = 0; cc < 32; ++cc) {
#pragma unroll
            for (int r = 0; r < 8; ++r)
                racc[r] = fmaf(WredT[(cb * 32 + cc) * CR + q * 8 + r], xv[cc], racc[r]);
        }
    }
#pragma unroll
    for (int r = 0; r < 8; ++r) sm.red[p][q * 8 + r] = racc[r];

    // ---- prefetch chunk 0 (channels 32q..32q+3): 12 rows of 66 as float2 ----
    float2 nv[12];
    if (p < 33) {
        const float* base = xb + (size_t)(32 * q) * CHW + (size_t)h * WIN + w0 + 2 * p;
#pragma unroll
        for (int rep = 0; rep < 12; ++rep)
            nv[rep] = *(const float2*)(base + (rep / 3) * CHW + (rep % 3) * WIN);
    }

    // barrier 1: red writes visible to all waves (vmcnt loads stay in flight)
    lgkm_barrier();

    // ---- stage 2: kern[18] for groups {2q,2q+1}, registers only ----
    float kern[18];
#pragma unroll
    for (int k = 0; k < 18; ++k) kern[k] = bkern[18 * q + k];
#pragma unroll
    for (int r = 0; r < CR; ++r) {
        float rv = sm.red[p][r];
#pragma unroll
        for (int k = 0; k < 18; ++k)
            kern[k] = fmaf(Wkern[(18 * q + k) * CR + r], rv, kern[k]);
    }

    // barrier 2: everyone done READING red -> safe to overlay with xs
    lgkm_barrier();

    // write chunk 0 (compiler inserts vmcnt wait on nv)
    if (p < 33) {
#pragma unroll
        for (int rep = 0; rep < 12; ++rep)
            *(float2*)&sm.xs[q][rep][2 * p] = nv[rep];
    }
    lds_fence();

    // ---- stage 3: 8 chunks x 4 channels, wave-private, barrier-free ----
    float* op = out + (((size_t)(b * C + 32 * q)) * HH + h) * WW + w0 + p;

#pragma unroll
    for (int ch = 0; ch < 8; ++ch) {
        // issue next-chunk loads early (hide under this chunk's consume)
        if (ch < 7 && p < 33) {
            const float* base = xb + (size_t)(32 * q + 4 * (ch + 1)) * CHW
                                   + (size_t)h * WIN + w0 + 2 * p;
#pragma unroll
            for (int rep = 0; rep < 12; ++rep)
                nv[rep] = *(const float2*)(base + (rep / 3) * CHW + (rep % 3) * WIN);
        }
        // consume chunk ch
#pragma unroll
        for (int m = 0; m < 4; ++m) {
            float acc = 0.f;
#pragma unroll
            for (int i = 0; i < 3; ++i)
#pragma unroll
                for (int j = 0; j < 3; ++j)
                    acc = fmaf(kern[9 * (ch >> 2) + 3 * i + j],
                               sm.xs[q][3 * m + i][p + j], acc);
            op[(size_t)(4 * ch + m) * HH * WW] = acc;
        }
        // overwrite wave-private rows with next chunk, fence for next iter
        if (ch < 7) {
            if (p < 33) {
#pragma unroll
                for (int rep = 0; rep < 12; ++rep)
                    *(float2*)&sm.xs[q][rep][2 * p] = nv[rep];
            }
            lds_fence();
        }
    }
}
} // namespace

extern "C" void kernel_launch(void* const* d_in, const int* in_sizes, int n_in,
                              void* d_out, int out_size, void* d_ws, size_t ws_size,
                              hipStream_t stream) {
    const float* x     = (const float*)d_in[0];
    const float* Wred  = (const float*)d_in[1];
    const float* bred  = (const float*)d_in[2];
    const float* Wkern = (const float*)d_in[3];
    const float* bkern = (const float*)d_in[4];
    float* out   = (float*)d_out;
    float* WredT = (float*)d_ws;   // 16 KB scratch

    transpose_wred<<<16, 256, 0, stream>>>(Wred, WredT);

    // 8 b * 128 h * 2 wseg = 2048 blocks
    invol_fused<<<2048, 256, 0, stream>>>(x, WredT, bred, Wkern, bkern, out);
}

// Round 7
// 78.211 us; speedup vs baseline: 2.7325x; 2.7325x over previous
//
#include <hip/hip_runtime.h>

namespace {
constexpr int HIN = 130, WIN = 130;
constexpr int HH = 128, WW = 128;
constexpr int C = 128, CR = 32, B = 8;
constexpr int CHW = HIN * WIN;   // 16900

// Transpose W_reduce (32x128) -> WredT (128x32): r-loop reads contiguous
// uniform floats (scalarized to s_load_dwordx*).
__global__ void transpose_wred(const float* __restrict__ Wred, float* __restrict__ WredT) {
    int idx = blockIdx.x * 256 + threadIdx.x;   // 4096 elements
    int r = idx >> 7;
    int c = idx & 127;
    WredT[c * CR + r] = Wred[r * C + c];
}

// In-wave LDS ordering fence (rule-18 pattern): cross-lane write->read in
// wave-private LDS is invisible to per-lane alias analysis; lgkmcnt(0) +
// sched_barrier(0) orders it without a workgroup barrier.
__device__ __forceinline__ void lds_fence() {
    asm volatile("s_waitcnt lgkmcnt(0)" ::: "memory");
    __builtin_amdgcn_sched_barrier(0);
}

// lgkm-only workgroup barrier: leaves global prefetch (vmcnt) in flight.
__device__ __forceinline__ void lgkm_barrier() {
    asm volatile("s_waitcnt lgkmcnt(0)\n\ts_barrier" ::: "memory");
    __builtin_amdgcn_sched_barrier(0);
}

// Block = 256 threads = 64 pixels (lanes) x 4 waves.
// Wave q owns channels [32q,32q+32) and groups {2q,2q+1}. red_lds and the
// stage-3 tap buffer OVERLAY (union) -> 12.8 KB/block. With VGPR <= 64 the
// HW then fits 8 blocks/CU = the whole 2048-block grid in ONE round (grid
// is exactly 8 blocks/CU of work) -> no tail round.
// NOTE: launch_bounds stays (256,4): forcing 8 waves/SIMD (R6) cut VGPR to
// 32 and spilled (WRITE_SIZE 65->507 MB). Residency must come from the
// natural 48-reg allocation, not a forced cap.
__global__ __launch_bounds__(256, 4) void invol_fused(
    const float* __restrict__ x,      // [B][C][130][130]
    const float* __restrict__ WredT,  // [128][32]
    const float* __restrict__ bred,   // [32]
    const float* __restrict__ Wkern,  // [72][32]
    const float* __restrict__ bkern,  // [72]
    float* __restrict__ out)          // [B][C][128][128]
{
    __shared__ union SM {
        float red[64][CR + 1];   // 8448 B   (stage 1/2)
        float xs[4][12][66];     // 12672 B  (stage 3, wave-private rows)
    } sm;

    const int t = threadIdx.x;
    const int p = t & 63;
    const int q = __builtin_amdgcn_readfirstlane(t >> 6);

    // XCD-chunked swizzle: XCD k owns batch k -> h-adjacent blocks (sharing
    // 2/3 of their row footprint) land on the same L2.
    const int orig = blockIdx.x;
    const int blk  = (orig & 7) * 256 + (orig >> 3);   // bijective (2048 % 8 == 0)
    const int b    = blk >> 8;
    const int h    = (blk >> 1) & (HH - 1);
    const int w0   = (blk & 1) << 6;

    const float* xb = x + (size_t)b * C * CHW;

    // ---- stage 1: red[8q..8q+8) ----
    const float* xc = xb + (size_t)(h + 1) * WIN + (w0 + p + 1);
    float racc[8];
#pragma unroll
    for (int r = 0; r < 8; ++r) racc[r] = bred[q * 8 + r];

#pragma unroll
    for (int cb = 0; cb < 4; ++cb) {
        float xv[32];
#pragma unroll
        for (int cc = 0; cc < 32; ++cc)
            xv[cc] = xc[(size_t)(cb * 32 + cc) * CHW];
#pragma unroll
        for (int cc = 0; cc < 32; ++cc) {
#pragma unroll
            for (int r = 0; r < 8; ++r)
                racc[r] = fmaf(WredT[(cb * 32 + cc) * CR + q * 8 + r], xv[cc], racc[r]);
        }
    }
#pragma unroll
    for (int r = 0; r < 8; ++r) sm.red[p][q * 8 + r] = racc[r];

    // ---- prefetch chunk 0 (channels 32q..32q+3): 12 rows of 66 as float2 ----
    float2 nv[12];
    if (p < 33) {
        const float* base = xb + (size_t)(32 * q) * CHW + (size_t)h * WIN + w0 + 2 * p;
#pragma unroll
        for (int rep = 0; rep < 12; ++rep)
            nv[rep] = *(const float2*)(base + (rep / 3) * CHW + (rep % 3) * WIN);
    }

    // barrier 1: red writes visible to all waves (vmcnt loads stay in flight)
    lgkm_barrier();

    // ---- stage 2: kern[18] for groups {2q,2q+1}, registers only ----
    float kern[18];
#pragma unroll
    for (int k = 0; k < 18; ++k) kern[k] = bkern[18 * q + k];
#pragma unroll
    for (int r = 0; r < CR; ++r) {
        float rv = sm.red[p][r];
#pragma unroll
        for (int k = 0; k < 18; ++k)
            kern[k] = fmaf(Wkern[(18 * q + k) * CR + r], rv, kern[k]);
    }

    // barrier 2: everyone done READING red -> safe to overlay with xs
    lgkm_barrier();

    // write chunk 0 (compiler inserts vmcnt wait on nv)
    if (p < 33) {
#pragma unroll
        for (int rep = 0; rep < 12; ++rep)
            *(float2*)&sm.xs[q][rep][2 * p] = nv[rep];
    }
    lds_fence();

    // ---- stage 3: 8 chunks x 4 channels, wave-private, barrier-free ----
    float* op = out + (((size_t)(b * C + 32 * q)) * HH + h) * WW + w0 + p;

#pragma unroll
    for (int ch = 0; ch < 8; ++ch) {
        // issue next-chunk loads early (hide under this chunk's consume)
        if (ch < 7 && p < 33) {
            const float* base = xb + (size_t)(32 * q + 4 * (ch + 1)) * CHW
                                   + (size_t)h * WIN + w0 + 2 * p;
#pragma unroll
            for (int rep = 0; rep < 12; ++rep)
                nv[rep] = *(const float2*)(base + (rep / 3) * CHW + (rep % 3) * WIN);
        }
        // consume chunk ch
#pragma unroll
        for (int m = 0; m < 4; ++m) {
            float acc = 0.f;
#pragma unroll
            for (int i = 0; i < 3; ++i)
#pragma unroll
                for (int j = 0; j < 3; ++j)
                    acc = fmaf(kern[9 * (ch >> 2) + 3 * i + j],
                               sm.xs[q][3 * m + i][p + j], acc);
            op[(size_t)(4 * ch + m) * HH * WW] = acc;
        }
        // overwrite wave-private rows with next chunk, fence for next iter
        if (ch < 7) {
            if (p < 33) {
#pragma unroll
                for (int rep = 0; rep < 12; ++rep)
                    *(float2*)&sm.xs[q][rep][2 * p] = nv[rep];
            }
            lds_fence();
        }
    }
}
} // namespace

extern "C" void kernel_launch(void* const* d_in, const int* in_sizes, int n_in,
                              void* d_out, int out_size, void* d_ws, size_t ws_size,
                              hipStream_t stream) {
    const float* x     = (const float*)d_in[0];
    const float* Wred  = (const float*)d_in[1];
    const float* bred  = (const float*)d_in[2];
    const float* Wkern = (const float*)d_in[3];
    const float* bkern = (const float*)d_in[4];
    float* out   = (float*)d_out;
    float* WredT = (float*)d_ws;   // 16 KB scratch

    transpose_wred<<<16, 256, 0, stream>>>(Wred, WredT);

    // 8 b * 128 h * 2 wseg = 2048 blocks
    invol_fused<<<2048, 256, 0, stream>>>(x, WredT, bred, Wkern, bkern, out);
}